// Round 1
// baseline (308.679 us; speedup 1.0000x reference)
//
#include <hip/hip_runtime.h>
#include <math.h>

// ---------------------------------------------------------------------------
// ActorNetwork fused kernel, round 1 (fp32 VALU, SGPR-streamed weights).
//
// Exact algebraic folds (no approximation):
//   * W_cq / W_ck are dead (softmax over seq_len=1 == 1).
//   * score = intru . (own_e @ (W_q^T W_k))      [precomputed wQK]
//   * v_att = (sum_n alpha_n intru_n) @ W_v.T    [pool-then-project]
//   * mo    = concat @ W_fold^T + b_mo,  W_fold = blockdiag-fold of W_mo,W_cv
//
// Layout: 8 lanes per batch element; each lane owns 4 neighbors end-to-end
// with a private online-softmax (m,S,P[64]) state; group-combined via
// shfl_xor. Hot loop weights (W_s1 rows, W_s2^T rows) are wave-uniform ->
// compiler emits s_load; every FMA is v_fma(v, s, v).
// ---------------------------------------------------------------------------

#define WS_S2T   0        // [64][64]  W_s2^T
#define WS_OWNT  4096     // [16][64]  W_own^T
#define WS_QK    5120     // [64][64]  W_q^T @ W_k
#define WS_FOLDT 9216     // [192][128] W_fold^T
#define WS_A1T   33792    // [128][64] W_a1^T
#define WS_ENVT  41984    // [64][64]  W_env^T
#define WS_TOTAL 46080

__global__ void actor_setup(
    const float* __restrict__ wOwn, const float* __restrict__ wEnv,
    const float* __restrict__ wS2,  const float* __restrict__ wQ,
    const float* __restrict__ wK,   const float* __restrict__ wCv,
    const float* __restrict__ wMo,  const float* __restrict__ wA1,
    float* __restrict__ ws)
{
    int t = blockIdx.x * 256 + threadIdx.x;
    if (t < 4096) {                        // wS2T[k][d] = W_s2[d][k]
        int k = t >> 6, d = t & 63;
        ws[WS_S2T + t] = wS2[d * 64 + k];
    } else if (t < 5120) {                 // wOwnT[k][d] = W_own[d][k]
        int u = t - 4096; int k = u >> 6, d = u & 63;
        ws[t] = wOwn[d * 16 + k];
    } else if (t < 9216) {                 // wQK[e][dp] = sum_d W_q[d][e]*W_k[d][dp]
        int u = t - 5120; int e = u >> 6, dp = u & 63;
        float acc = 0.f;
        for (int d = 0; d < 64; ++d) acc += wQ[d * 64 + e] * wK[d * 64 + dp];
        ws[t] = acc;
    } else if (t < 33792) {                // wFoldT[i][j], i = h*64+dp
        int u = t - 9216; int i = u >> 7, j = u & 127;
        int h = i >> 6, dp = i & 63;
        float acc = 0.f;
        for (int d = 0; d < 64; ++d)
            acc += wMo[j * 192 + h * 64 + d] * wCv[d * 64 + dp];
        ws[t] = acc;
    } else if (t < 41984) {                // wA1T[j][o] = W_a1[o][j]
        int u = t - 33792; int j = u >> 6, o = u & 63;
        ws[t] = wA1[o * 128 + j];
    } else if (t < WS_TOTAL) {             // wEnvT[k][d] = W_env[d][k]
        int u = t - 41984; int k = u >> 6, d = u & 63;
        ws[t] = wEnv[d * 64 + k];
    }
}

#define ELPB 32   // batch elements per 256-thread block (8 lanes each)

__global__ __launch_bounds__(256, 2) void actor_main(
    const float* __restrict__ s0g, const float* __restrict__ s1g,
    const float* __restrict__ s2g,
    const float* __restrict__ bOwn, const float* __restrict__ bEnv,
    const float* __restrict__ wS1,  const float* __restrict__ bS1,
    const float* __restrict__ bS2,  const float* __restrict__ wV,
    const float* __restrict__ bMo,  const float* __restrict__ bA1,
    const float* __restrict__ wA2,  const float* __restrict__ bA2,
    const float* __restrict__ ws,   float* __restrict__ outg)
{
    const float* __restrict__ wS2T   = ws + WS_S2T;
    const float* __restrict__ wOwnT  = ws + WS_OWNT;
    const float* __restrict__ wQK    = ws + WS_QK;
    const float* __restrict__ wFoldT = ws + WS_FOLDT;
    const float* __restrict__ wA1T   = ws + WS_A1T;
    const float* __restrict__ wEnvT  = ws + WS_ENVT;

    __shared__ float concatL[ELPB][196];   // [own 0:64 | env 64:128 | vatt 128:192], pad->196
    __shared__ float moL[ELPB][132];       // qk broadcast, then mo broadcast; pad->132

    const int tid = threadIdx.x;
    const int el  = tid >> 3;        // element within block
    const int g   = tid & 7;         // lane within 8-lane group
    const int b   = blockIdx.x * ELPB + el;

    // ---------------- own_e slice (8 dims/lane) -> concatL[0..63]
    float s0r[16];
    {
        const float4* p = reinterpret_cast<const float4*>(s0g + (size_t)b * 16);
        #pragma unroll
        for (int q = 0; q < 4; ++q) {
            float4 v = p[q];
            s0r[q*4+0]=v.x; s0r[q*4+1]=v.y; s0r[q*4+2]=v.z; s0r[q*4+3]=v.w;
        }
    }
    {
        float4 b0 = *reinterpret_cast<const float4*>(bOwn + g*8);
        float4 b1 = *reinterpret_cast<const float4*>(bOwn + g*8 + 4);
        float ow[8] = {b0.x,b0.y,b0.z,b0.w,b1.x,b1.y,b1.z,b1.w};
        #pragma unroll
        for (int k = 0; k < 16; ++k) {
            float sk = s0r[k];
            const float* wr = wOwnT + k*64 + g*8;
            float4 w0 = *reinterpret_cast<const float4*>(wr);
            float4 w1 = *reinterpret_cast<const float4*>(wr + 4);
            ow[0]=fmaf(sk,w0.x,ow[0]); ow[1]=fmaf(sk,w0.y,ow[1]);
            ow[2]=fmaf(sk,w0.z,ow[2]); ow[3]=fmaf(sk,w0.w,ow[3]);
            ow[4]=fmaf(sk,w1.x,ow[4]); ow[5]=fmaf(sk,w1.y,ow[5]);
            ow[6]=fmaf(sk,w1.z,ow[6]); ow[7]=fmaf(sk,w1.w,ow[7]);
        }
        #pragma unroll
        for (int j = 0; j < 8; ++j) ow[j] = fmaxf(ow[j], 0.f);
        *reinterpret_cast<float4*>(&concatL[el][g*8])     = make_float4(ow[0],ow[1],ow[2],ow[3]);
        *reinterpret_cast<float4*>(&concatL[el][g*8 + 4]) = make_float4(ow[4],ow[5],ow[6],ow[7]);
    }
    __syncthreads();

    // ---------------- qkvec slice, broadcast through moL
    {
        float qs[8] = {0,0,0,0,0,0,0,0};
        #pragma unroll 2
        for (int e4 = 0; e4 < 16; ++e4) {
            float4 c4 = *reinterpret_cast<const float4*>(&concatL[el][e4*4]);
            #pragma unroll
            for (int q = 0; q < 4; ++q) {
                float oe = (q==0)?c4.x:(q==1)?c4.y:(q==2)?c4.z:c4.w;
                const float* wr = wQK + (e4*4+q)*64 + g*8;
                float4 w0 = *reinterpret_cast<const float4*>(wr);
                float4 w1 = *reinterpret_cast<const float4*>(wr + 4);
                qs[0]=fmaf(oe,w0.x,qs[0]); qs[1]=fmaf(oe,w0.y,qs[1]);
                qs[2]=fmaf(oe,w0.z,qs[2]); qs[3]=fmaf(oe,w0.w,qs[3]);
                qs[4]=fmaf(oe,w1.x,qs[4]); qs[5]=fmaf(oe,w1.y,qs[5]);
                qs[6]=fmaf(oe,w1.z,qs[6]); qs[7]=fmaf(oe,w1.w,qs[7]);
            }
        }
        *reinterpret_cast<float4*>(&moL[el][g*8])     = make_float4(qs[0],qs[1],qs[2],qs[3]);
        *reinterpret_cast<float4*>(&moL[el][g*8 + 4]) = make_float4(qs[4],qs[5],qs[6],qs[7]);
    }
    __syncthreads();

    float qk[64];
    #pragma unroll
    for (int d4 = 0; d4 < 16; ++d4) {
        float4 v = *reinterpret_cast<const float4*>(&moL[el][d4*4]);
        qk[d4*4+0]=v.x; qk[d4*4+1]=v.y; qk[d4*4+2]=v.z; qk[d4*4+3]=v.w;
    }

    // ---------------- neighbor loop: 4 neighbors/lane, online softmax
    float P[64];
    #pragma unroll
    for (int d = 0; d < 64; ++d) P[d] = 0.f;
    float mrun = -1e30f, Srun = 0.f;

    const float* s2b = s2g + (size_t)b * 512;
    #pragma unroll 1
    for (int it = 0; it < 4; ++it) {
        const int n = it*8 + g;
        float sj[16];
        {
            const float4* p = reinterpret_cast<const float4*>(s2b + n*16);
            #pragma unroll
            for (int q = 0; q < 4; ++q) {
                float4 v = p[q];
                sj[q*4+0]=v.x; sj[q*4+1]=v.y; sj[q*4+2]=v.z; sj[q*4+3]=v.w;
            }
        }
        float acc[64];
        #pragma unroll
        for (int d = 0; d < 64; ++d) acc[d] = bS2[d];       // uniform -> sgpr
        #pragma unroll 2
        for (int k = 0; k < 64; ++k) {
            float hk = bS1[k];
            const float* w1 = wS1 + k*16;                   // uniform -> s_load
            #pragma unroll
            for (int j = 0; j < 16; ++j) hk = fmaf(sj[j], w1[j], hk);
            hk = fmaxf(hk, 0.f);
            const float* w2 = wS2T + k*64;                  // uniform -> s_load
            #pragma unroll
            for (int d = 0; d < 64; ++d) acc[d] = fmaf(hk, w2[d], acc[d]);
        }
        float rs0=0,rs1=0,rs2=0,rs3=0, t0=0,t1=0,t2=0,t3=0;
        #pragma unroll
        for (int d = 0; d < 64; d += 4) {
            float a0=fmaxf(acc[d],0.f),  a1=fmaxf(acc[d+1],0.f);
            float a2=fmaxf(acc[d+2],0.f),a3=fmaxf(acc[d+3],0.f);
            acc[d]=a0; acc[d+1]=a1; acc[d+2]=a2; acc[d+3]=a3;
            rs0+=a0; rs1+=a1; rs2+=a2; rs3+=a3;
            t0=fmaf(a0,qk[d],t0);   t1=fmaf(a1,qk[d+1],t1);
            t2=fmaf(a2,qk[d+2],t2); t3=fmaf(a3,qk[d+3],t3);
        }
        float rs = (rs0+rs1)+(rs2+rs3);
        float sc = ((t0+t1)+(t2+t3)) * 0.125f;      // / sqrt(64)
        bool valid = (rs != 0.f);                   // mask: mean(relu)!=0 <=> sum!=0
        float scv = valid ? sc : -1e30f;
        float nm = fmaxf(mrun, scv);
        float ascale = __expf(mrun - nm);
        float w = valid ? __expf(sc - nm) : 0.f;
        Srun = fmaf(Srun, ascale, w);
        #pragma unroll
        for (int d = 0; d < 64; ++d) P[d] = fmaf(P[d], ascale, w*acc[d]);
        mrun = nm;
    }

    // ---------------- combine flash states across the 8-lane group
    #pragma unroll
    for (int msk = 1; msk <= 4; msk <<= 1) {
        float mo_ = __shfl_xor(mrun, msk, 64);
        float So_ = __shfl_xor(Srun, msk, 64);
        float nm  = fmaxf(mrun, mo_);
        float aa  = __expf(mrun - nm);
        float bb  = __expf(mo_  - nm);
        Srun = fmaf(Srun, aa, So_*bb);
        #pragma unroll
        for (int d = 0; d < 64; ++d) {
            float Po = __shfl_xor(P[d], msk, 64);
            P[d] = fmaf(P[d], aa, Po*bb);
        }
        mrun = nm;
    }
    {
        float inv = (Srun > 0.f) ? (1.f / Srun) : 0.f;   // all-masked -> v_att = 0
        #pragma unroll
        for (int d = 0; d < 64; ++d) P[d] *= inv;        // pooled (pre-W_v)
    }

    // ---------------- v_att slice -> concatL[128..191]
    {
        float va[8];
        #pragma unroll
        for (int jj = 0; jj < 8; ++jj) {
            const float* wr = wV + (g*8 + jj)*64;
            float a0=0,a1=0,a2=0,a3=0;
            #pragma unroll
            for (int dp = 0; dp < 64; dp += 4) {
                float4 w4 = *reinterpret_cast<const float4*>(wr + dp);
                a0 = fmaf(P[dp+0], w4.x, a0);
                a1 = fmaf(P[dp+1], w4.y, a1);
                a2 = fmaf(P[dp+2], w4.z, a2);
                a3 = fmaf(P[dp+3], w4.w, a3);
            }
            va[jj] = (a0+a1)+(a2+a3);
        }
        *reinterpret_cast<float4*>(&concatL[el][128 + g*8])     = make_float4(va[0],va[1],va[2],va[3]);
        *reinterpret_cast<float4*>(&concatL[el][128 + g*8 + 4]) = make_float4(va[4],va[5],va[6],va[7]);
    }

    // ---------------- env slice -> concatL[64..127]
    {
        float4 b0 = *reinterpret_cast<const float4*>(bEnv + g*8);
        float4 b1 = *reinterpret_cast<const float4*>(bEnv + g*8 + 4);
        float ev[8] = {b0.x,b0.y,b0.z,b0.w,b1.x,b1.y,b1.z,b1.w};
        const float* s1b = s1g + (size_t)b * 64;
        #pragma unroll 2
        for (int k4 = 0; k4 < 16; ++k4) {
            float4 sv = *reinterpret_cast<const float4*>(s1b + k4*4);
            #pragma unroll
            for (int q = 0; q < 4; ++q) {
                float sk = (q==0)?sv.x:(q==1)?sv.y:(q==2)?sv.z:sv.w;
                const float* wr = wEnvT + (k4*4+q)*64 + g*8;
                float4 w0 = *reinterpret_cast<const float4*>(wr);
                float4 w1 = *reinterpret_cast<const float4*>(wr + 4);
                ev[0]=fmaf(sk,w0.x,ev[0]); ev[1]=fmaf(sk,w0.y,ev[1]);
                ev[2]=fmaf(sk,w0.z,ev[2]); ev[3]=fmaf(sk,w0.w,ev[3]);
                ev[4]=fmaf(sk,w1.x,ev[4]); ev[5]=fmaf(sk,w1.y,ev[5]);
                ev[6]=fmaf(sk,w1.z,ev[6]); ev[7]=fmaf(sk,w1.w,ev[7]);
            }
        }
        #pragma unroll
        for (int j = 0; j < 8; ++j) ev[j] = fmaxf(ev[j], 0.f);
        *reinterpret_cast<float4*>(&concatL[el][64 + g*8])     = make_float4(ev[0],ev[1],ev[2],ev[3]);
        *reinterpret_cast<float4*>(&concatL[el][64 + g*8 + 4]) = make_float4(ev[4],ev[5],ev[6],ev[7]);
    }
    __syncthreads();

    // ---------------- mo = concat @ W_fold^T + b_mo  (16 outs/lane)
    float mo[16];
    {
        const float* bm = bMo + g*16;
        #pragma unroll
        for (int q = 0; q < 4; ++q) {
            float4 v = *reinterpret_cast<const float4*>(bm + q*4);
            mo[q*4+0]=v.x; mo[q*4+1]=v.y; mo[q*4+2]=v.z; mo[q*4+3]=v.w;
        }
    }
    #pragma unroll 2
    for (int i4 = 0; i4 < 48; ++i4) {
        float4 c4 = *reinterpret_cast<const float4*>(&concatL[el][i4*4]);
        #pragma unroll
        for (int q = 0; q < 4; ++q) {
            float ci = (q==0)?c4.x:(q==1)?c4.y:(q==2)?c4.z:c4.w;
            const float* wr = wFoldT + (i4*4+q)*128 + g*16;
            #pragma unroll
            for (int u = 0; u < 4; ++u) {
                float4 w4 = *reinterpret_cast<const float4*>(wr + u*4);
                mo[u*4+0]=fmaf(ci,w4.x,mo[u*4+0]);
                mo[u*4+1]=fmaf(ci,w4.y,mo[u*4+1]);
                mo[u*4+2]=fmaf(ci,w4.z,mo[u*4+2]);
                mo[u*4+3]=fmaf(ci,w4.w,mo[u*4+3]);
            }
        }
    }
    #pragma unroll
    for (int q = 0; q < 4; ++q)
        *reinterpret_cast<float4*>(&moL[el][g*16 + q*4]) =
            make_float4(mo[q*4],mo[q*4+1],mo[q*4+2],mo[q*4+3]);
    __syncthreads();

    // ---------------- a = relu(mo @ W_a1^T + b_a1)  (8 outs/lane)
    float av[8];
    {
        float4 b0 = *reinterpret_cast<const float4*>(bA1 + g*8);
        float4 b1 = *reinterpret_cast<const float4*>(bA1 + g*8 + 4);
        av[0]=b0.x; av[1]=b0.y; av[2]=b0.z; av[3]=b0.w;
        av[4]=b1.x; av[5]=b1.y; av[6]=b1.z; av[7]=b1.w;
    }
    #pragma unroll 2
    for (int j4 = 0; j4 < 32; ++j4) {
        float4 m4 = *reinterpret_cast<const float4*>(&moL[el][j4*4]);
        #pragma unroll
        for (int q = 0; q < 4; ++q) {
            float mj = (q==0)?m4.x:(q==1)?m4.y:(q==2)?m4.z:m4.w;
            const float* wr = wA1T + (j4*4+q)*64 + g*8;
            float4 w0 = *reinterpret_cast<const float4*>(wr);
            float4 w1 = *reinterpret_cast<const float4*>(wr + 4);
            av[0]=fmaf(mj,w0.x,av[0]); av[1]=fmaf(mj,w0.y,av[1]);
            av[2]=fmaf(mj,w0.z,av[2]); av[3]=fmaf(mj,w0.w,av[3]);
            av[4]=fmaf(mj,w1.x,av[4]); av[5]=fmaf(mj,w1.y,av[5]);
            av[6]=fmaf(mj,w1.z,av[6]); av[7]=fmaf(mj,w1.w,av[7]);
        }
    }
    #pragma unroll
    for (int j = 0; j < 8; ++j) av[j] = fmaxf(av[j], 0.f);

    // ---------------- out = tanh(a @ W_a2^T + b_a2)
    {
        float4 w0a = *reinterpret_cast<const float4*>(wA2 + g*8);
        float4 w0b = *reinterpret_cast<const float4*>(wA2 + g*8 + 4);
        float4 w1a = *reinterpret_cast<const float4*>(wA2 + 64 + g*8);
        float4 w1b = *reinterpret_cast<const float4*>(wA2 + 64 + g*8 + 4);
        float p0 = av[0]*w0a.x + av[1]*w0a.y + av[2]*w0a.z + av[3]*w0a.w
                 + av[4]*w0b.x + av[5]*w0b.y + av[6]*w0b.z + av[7]*w0b.w;
        float p1 = av[0]*w1a.x + av[1]*w1a.y + av[2]*w1a.z + av[3]*w1a.w
                 + av[4]*w1b.x + av[5]*w1b.y + av[6]*w1b.z + av[7]*w1b.w;
        #pragma unroll
        for (int msk = 1; msk <= 4; msk <<= 1) {
            p0 += __shfl_xor(p0, msk, 64);
            p1 += __shfl_xor(p1, msk, 64);
        }
        if (g == 0) {
            float o0 = tanhf(p0 + bA2[0]);
            float o1 = tanhf(p1 + bA2[1]);
            *reinterpret_cast<float2*>(outg + (size_t)b * 2) = make_float2(o0, o1);
        }
    }
}

extern "C" void kernel_launch(void* const* d_in, const int* in_sizes, int n_in,
                              void* d_out, int out_size, void* d_ws, size_t ws_size,
                              hipStream_t stream) {
    const float* s0   = (const float*)d_in[0];
    const float* s1   = (const float*)d_in[1];
    const float* s2   = (const float*)d_in[2];
    const float* wOwn = (const float*)d_in[3];
    const float* bOwn = (const float*)d_in[4];
    const float* wEnv = (const float*)d_in[5];
    const float* bEnv = (const float*)d_in[6];
    const float* wS1  = (const float*)d_in[7];
    const float* bS1  = (const float*)d_in[8];
    const float* wS2  = (const float*)d_in[9];
    const float* bS2  = (const float*)d_in[10];
    const float* wQ   = (const float*)d_in[11];
    const float* wK   = (const float*)d_in[12];
    const float* wV   = (const float*)d_in[13];
    // d_in[14] (W_cq) and d_in[15] (W_ck) are dead code in the reference.
    const float* wCv  = (const float*)d_in[16];
    const float* wMo  = (const float*)d_in[17];
    const float* bMo  = (const float*)d_in[18];
    const float* wA1  = (const float*)d_in[19];
    const float* bA1  = (const float*)d_in[20];
    const float* wA2  = (const float*)d_in[21];
    const float* bA2  = (const float*)d_in[22];
    float* ws  = (float*)d_ws;
    float* out = (float*)d_out;

    hipLaunchKernelGGL(actor_setup, dim3(WS_TOTAL / 256), dim3(256), 0, stream,
                       wOwn, wEnv, wS2, wQ, wK, wCv, wMo, wA1, ws);
    hipLaunchKernelGGL(actor_main, dim3(16384 / ELPB), dim3(256), 0, stream,
                       s0, s1, s2, bOwn, bEnv, wS1, bS1, bS2, wV,
                       bMo, bA1, wA2, bA2, ws, out);
}